// Round 3
// baseline (1813.619 us; speedup 1.0000x reference)
//
#include <hip/hip_runtime.h>
#include <hip/hip_bf16.h>
#include <cstdint>

// Problem constants
#define BB 16
#define NN 4096
#define MM 1024
#define KNB 16
#define CIN 64
#define COUT 128
#define RTOT (BB*MM*KNB)   // 262144 rows

// ---------- helpers ----------
__device__ __forceinline__ float bflo(uint32_t u){ return __uint_as_float(u << 16); }
__device__ __forceinline__ float bfhi(uint32_t u){ return __uint_as_float(u & 0xffff0000u); }
__device__ __forceinline__ uint32_t f2bf_pk(float a, float b){
  uint32_t ua = __float_as_uint(a), ub = __float_as_uint(b);
  ua += 0x7fffu + ((ua >> 16) & 1u);   // RNE (values are finite, no NaN handling needed)
  ub += 0x7fffu + ((ub >> 16) & 1u);
  return (ua >> 16) | (ub & 0xffff0000u);
}

// ---------- K0a: transpose x1 [B,64,N] -> xt [B,N,64] ----------
__global__ __launch_bounds__(256) void k_transpose(const float* __restrict__ x1, float* __restrict__ xt){
  __shared__ float t[64][65];
  int b = blockIdx.x >> 6, nt = blockIdx.x & 63;
  int n0 = nt*64, tid = threadIdx.x;
  int c = tid>>2, q = tid&3;
  const float* src = x1 + ((size_t)(b*64 + c))*NN + n0 + q*16;
  #pragma unroll
  for (int j=0;j<4;j++){
    float4 f = *(const float4*)(src + j*4);
    t[c][q*16+j*4+0]=f.x; t[c][q*16+j*4+1]=f.y; t[c][q*16+j*4+2]=f.z; t[c][q*16+j*4+3]=f.w;
  }
  __syncthreads();
  int n = tid>>2, c0 = q*16;
  float* dst = xt + ((size_t)(b*NN + n0 + n))*64 + c0;
  #pragma unroll
  for (int j=0;j<4;j++){
    float4 o;
    o.x=t[c0+j*4+0][n]; o.y=t[c0+j*4+1][n]; o.z=t[c0+j*4+2][n]; o.w=t[c0+j*4+3][n];
    *(float4*)(dst + j*4) = o;
  }
}

// ---------- K0b: n1[i] = |p|^2 (np op order: (x*x + y*y) + z*z, plain ops) ----------
__global__ __launch_bounds__(256) void k_norms(const float* __restrict__ p1, float* __restrict__ n1){
  int i = blockIdx.x*256 + threadIdx.x;      // < B*N = 65536
  float x = p1[(size_t)i*3+0], y = p1[(size_t)i*3+1], z = p1[(size_t)i*3+2];
  n1[i] = __fadd_rn(__fadd_rn(__fmul_rn(x,x),__fmul_rn(y,y)),__fmul_rn(z,z));
}

// ---------- K1: farthest point sampling v3 ----------
// Selection semantics identical to v1/v2 (exact np-order distance arithmetic,
// first-index max via index-ordered tournament, lowest-global-index tie-break in
// all cross-lane merges). v3 mechanics:
//  - 256 threads (16 pts/lane): 1 wave/SIMD -> no dual-wave issue contention
//  - balanced tournament tree for per-lane argmax (depth 4 vs 16-chain)
//  - 16 row-winner candidates; post-barrier reduce is 4 DPP steps, no ds_swizzle
__global__ __launch_bounds__(256) void k_fps(const float* __restrict__ p1,
                                             float* __restrict__ outp2, float* __restrict__ p2w){
  __shared__ float pc[NN*3];          // 48 KB point coords
  __shared__ float4 sel[MM];          // 16 KB selected centroids
  __shared__ float2 cand[2][16];      // double-buffered row-16 winners (4 waves x 4 rows)
  int b = blockIdx.x, tid = threadIdx.x;
  int lane = tid & 63, wid = tid >> 6;
  const float* pb = p1 + (size_t)b*NN*3;
  float4 f[12];
  const float4* src = (const float4*)(pb + tid*48);
  #pragma unroll
  for (int j=0;j<12;j++) f[j] = src[j];
  float4* lp = (float4*)(pc + tid*48);
  #pragma unroll
  for (int j=0;j<12;j++) lp[j] = f[j];
  const float* fa = (const float*)f;
  float px[16],py[16],pz[16],dist[16];
  #pragma unroll
  for (int j=0;j<16;j++){ px[j]=fa[3*j]; py[j]=fa[3*j+1]; pz[j]=fa[3*j+2]; dist[j]=1e10f; }
  __syncthreads();
  float cx = pc[0], cy = pc[1], cz = pc[2];
  if (tid==0) sel[0] = make_float4(cx, cy, cz, 0.f);
  int g0 = tid*16;

  #define DPP_STEP(ctrl) { \
    int ov_i = __builtin_amdgcn_update_dpp(__float_as_int(mval), __float_as_int(mval), (ctrl), 0xf, 0xf, false); \
    int oi   = __builtin_amdgcn_update_dpp(midx, midx, (ctrl), 0xf, 0xf, false); \
    float ov = __int_as_float(ov_i); \
    if (ov > mval || (ov == mval && oi < midx)){ mval = ov; midx = oi; } }

  for (int i=1;i<MM;i++){
    // distance update (exact np op order), results in nd[]
    float nd[16];
    #pragma unroll
    for (int j=0;j<16;j++){
      float dx=__fsub_rn(px[j],cx), dy=__fsub_rn(py[j],cy), dz=__fsub_rn(pz[j],cz);
      float d = __fadd_rn(__fadd_rn(__fmul_rn(dx,dx),__fmul_rn(dy,dy)),__fmul_rn(dz,dz));
      nd[j] = fminf(dist[j], d); dist[j] = nd[j];
    }
    // per-lane argmax: index-ordered tournament (left wins ties -> first-index max)
    float tv[8]; int ti[8];
    #pragma unroll
    for (int j=0;j<8;j++){
      bool r = nd[2*j+1] > nd[2*j];
      tv[j] = r ? nd[2*j+1] : nd[2*j];
      ti[j] = g0 + 2*j + (r ? 1 : 0);
    }
    #pragma unroll
    for (int j=0;j<4;j++){
      bool r = tv[2*j+1] > tv[2*j];
      tv[j] = r ? tv[2*j+1] : tv[2*j];
      ti[j] = r ? ti[2*j+1] : ti[2*j];
    }
    #pragma unroll
    for (int j=0;j<2;j++){
      bool r = tv[2*j+1] > tv[2*j];
      tv[j] = r ? tv[2*j+1] : tv[2*j];
      ti[j] = r ? ti[2*j+1] : ti[2*j];
    }
    float mval = (tv[1] > tv[0]) ? tv[1] : tv[0];
    int   midx = (tv[1] > tv[0]) ? ti[1] : ti[0];
    // reduce within each row of 16 lanes (pure DPP)
    DPP_STEP(0xB1);   // quad_perm xor1
    DPP_STEP(0x4E);   // quad_perm xor2
    DPP_STEP(0x124);  // row_ror:4
    DPP_STEP(0x128);  // row_ror:8
    int pbuf = i & 1;
    if ((lane & 15) == 0) cand[pbuf][wid*4 + (lane>>4)] = make_float2(mval, __int_as_float(midx));
    __syncthreads();
    // all lanes read the 16 candidates (replicated per row-16) and reduce via DPP
    float2 c = cand[pbuf][lane & 15];
    mval = c.x; midx = __float_as_int(c.y);
    DPP_STEP(0xB1);
    DPP_STEP(0x4E);
    DPP_STEP(0x124);
    DPP_STEP(0x128);
    cx = pc[midx*3+0]; cy = pc[midx*3+1]; cz = pc[midx*3+2];
    if (tid==0) sel[i] = make_float4(cx, cy, cz, 0.f);
  }
  #undef DPP_STEP
  __syncthreads();
  for (int e = tid; e < MM; e += 256){
    float4 s = sel[e];
    float n2 = __fadd_rn(__fadd_rn(__fmul_rn(s.x,s.x),__fmul_rn(s.y,s.y)),__fmul_rn(s.z,s.z));
    float* o = outp2 + ((size_t)b*MM + e)*3;
    o[0]=s.x; o[1]=s.y; o[2]=s.z;
    *(float4*)(p2w + ((size_t)b*MM + e)*4) = make_float4(s.x, s.y, s.z, n2);
  }
}

// ---------- K2: kNN, one wave per query ----------
__global__ __launch_bounds__(256) void k_knn(const float* __restrict__ p1, const float* __restrict__ n1,
                                             const float* __restrict__ p2w, int* __restrict__ iknn){
  int tid = threadIdx.x, lane = tid & 63, w = tid >> 6;
  int q = blockIdx.x*4 + w;
  int b = q >> 10;
  const float4 qv = *(const float4*)(p2w + (size_t)q*4);   // x,y,z,|q|^2
  const float* pb = p1 + (size_t)b*NN*3;
  const float* nb = n1 + (size_t)b*NN;
  float bd[16]; int bi[16];
  #pragma unroll
  for (int s=0;s<16;s++){ bd[s] = 1e30f; bi[s] = 0; }
  float wv = 1e30f; int wslot = 0;
  for (int t=0;t<64;t++){
    int c = t*64 + lane;
    float x = pb[(size_t)c*3+0], y = pb[(size_t)c*3+1], z = pb[(size_t)c*3+2];
    float nn = nb[c];
    float dot = fmaf(qv.z, z, fmaf(qv.y, y, __fmul_rn(qv.x, x)));   // BLAS-style fma chain
    float d2 = __fsub_rn(__fadd_rn(qv.w, nn), __fmul_rn(2.0f, dot));
    if (d2 < wv){
      #pragma unroll
      for (int s=0;s<16;s++) if (s==wslot){ bd[s]=d2; bi[s]=c; }
      wv = bd[0]; wslot = 0;
      #pragma unroll
      for (int s=1;s<16;s++) if (bd[s] > wv){ wv = bd[s]; wslot = s; }
    }
  }
  float lv = bd[0]; int ls = 0;
  #pragma unroll
  for (int s=1;s<16;s++) if (bd[s] < lv){ lv = bd[s]; ls = s; }
  for (int r=0;r<16;r++){
    float rv = lv; int rl = lane;
    #pragma unroll
    for (int off=32; off>=1; off>>=1){
      float ov = __shfl_xor(rv, off); int ol = __shfl_xor(rl, off);
      if (ov < rv || (ov == rv && ol < rl)){ rv = ov; rl = ol; }
    }
    if (lane == rl){
      int idx = 0;
      #pragma unroll
      for (int s=0;s<16;s++) if (s==ls) idx = bi[s];
      iknn[(size_t)q*16 + r] = idx;
      #pragma unroll
      for (int s=0;s<16;s++) if (s==ls) bd[s] = 1e30f;
      lv = bd[0]; ls = 0;
      #pragma unroll
      for (int s=1;s<16;s++) if (bd[s] < lv){ lv = bd[s]; ls = s; }
    }
  }
}

// ---------- K4: GEMM1 (fused gather) + stats atomics, h1 out (bf16) ----------
__global__ __launch_bounds__(256) void k_gemm1(const float* __restrict__ xt, const int* __restrict__ iknn,
                                               const float* __restrict__ p1, const float* __restrict__ p2w,
                                               const float* __restrict__ w1,
                                               __hip_bfloat16* __restrict__ h1, float* __restrict__ stats){
  __shared__ float At[68*64];          // At[c][row], c in [0,67)
  __shared__ float Wt[67*128];         // Wt[c][o]
  __shared__ float ssum[128], ssq[128];
  int tid = threadIdx.x;
  int r0 = blockIdx.x * 64;
  int b = r0 >> 14;                    // 16384 rows per batch
  for (int e = tid; e < 8576; e += 256){
    int o = e / 67; int c = e - o*67;
    Wt[c*128 + o] = w1[e];
  }
  if (tid < 128){ ssum[tid] = 0.f; ssq[tid] = 0.f; }
  int row = tid >> 2, sub = tid & 3;
  {
    int r = r0 + row;
    int n = iknn[r];
    int mg = r >> 4;                   // global (b*M+m)
    const float* xr = xt + ((size_t)(b*NN + n))*64 + sub*16;
    #pragma unroll
    for (int j=0;j<4;j++){
      float4 v = *(const float4*)(xr + j*4);
      int cb = 3 + sub*16 + j*4;
      At[(cb+0)*64+row]=v.x; At[(cb+1)*64+row]=v.y; At[(cb+2)*64+row]=v.z; At[(cb+3)*64+row]=v.w;
    }
    if (sub==0){
      const float* pp = p1 + ((size_t)(b*NN + n))*3;
      const float* qq = p2w + (size_t)mg*4;
      At[0*64+row] = __fsub_rn(pp[0], qq[0]);
      At[1*64+row] = __fsub_rn(pp[1], qq[1]);
      At[2*64+row] = __fsub_rn(pp[2], qq[2]);
    }
  }
  __syncthreads();
  int tx = tid & 15, ty = tid >> 4;
  float acc[4][8];
  #pragma unroll
  for (int i=0;i<4;i++)
    #pragma unroll
    for (int j=0;j<8;j++) acc[i][j] = 0.f;
  for (int c=0;c<67;c++){
    float4 a  = *(const float4*)(At + c*64 + ty*4);
    float4 b0 = *(const float4*)(Wt + c*128 + tx*4);
    float4 b1 = *(const float4*)(Wt + c*128 + 64 + tx*4);
    float ar[4] = {a.x, a.y, a.z, a.w};
    #pragma unroll
    for (int i=0;i<4;i++){
      acc[i][0]=fmaf(ar[i],b0.x,acc[i][0]); acc[i][1]=fmaf(ar[i],b0.y,acc[i][1]);
      acc[i][2]=fmaf(ar[i],b0.z,acc[i][2]); acc[i][3]=fmaf(ar[i],b0.w,acc[i][3]);
      acc[i][4]=fmaf(ar[i],b1.x,acc[i][4]); acc[i][5]=fmaf(ar[i],b1.y,acc[i][5]);
      acc[i][6]=fmaf(ar[i],b1.z,acc[i][6]); acc[i][7]=fmaf(ar[i],b1.w,acc[i][7]);
    }
  }
  #pragma unroll
  for (int i=0;i<4;i++){
    size_t rr = (size_t)(r0 + ty*4 + i);
    uint2 u0, u1;
    u0.x = f2bf_pk(acc[i][0], acc[i][1]); u0.y = f2bf_pk(acc[i][2], acc[i][3]);
    u1.x = f2bf_pk(acc[i][4], acc[i][5]); u1.y = f2bf_pk(acc[i][6], acc[i][7]);
    *(uint2*)(h1 + rr*128 + tx*4)      = u0;
    *(uint2*)(h1 + rr*128 + 64 + tx*4) = u1;
  }
  #pragma unroll
  for (int j=0;j<8;j++){
    int col = (j<4) ? (tx*4+j) : (64 + tx*4 + (j-4));
    float s  = acc[0][j]+acc[1][j]+acc[2][j]+acc[3][j];
    float q2 = acc[0][j]*acc[0][j] + acc[1][j]*acc[1][j] + acc[2][j]*acc[2][j] + acc[3][j]*acc[3][j];
    atomicAdd(&ssum[col], s); atomicAdd(&ssq[col], q2);
  }
  __syncthreads();
  if (tid < 128){ atomicAdd(&stats[tid], ssum[tid]); atomicAdd(&stats[128+tid], ssq[tid]); }
}

// ---------- K5/K7: finalize BN scale/shift ----------
__global__ void k_fin(const float* __restrict__ g, const float* __restrict__ bbias,
                      float* __restrict__ stats, int io, int oo){
  int o = threadIdx.x;
  float inv = 1.0f / (float)RTOT;
  float mean = stats[io+o] * inv;
  float var  = stats[io+128+o] * inv - mean*mean;
  float rs = 1.0f / sqrtf(var + 1e-5f);
  float sc = g[o] * rs;
  stats[oo+o]     = sc;
  stats[oo+128+o] = bbias[o] - mean*sc;
}

// ---------- K6: GEMM2 (bn1+relu fused on load) + stats atomics, h2 out ----------
__global__ __launch_bounds__(256) void k_gemm2(const __hip_bfloat16* __restrict__ h1,
                                               const float* __restrict__ w2,
                                               const float* __restrict__ stats,
                                               __hip_bfloat16* __restrict__ h2){
  __shared__ float At[64*64];          // At[c][row], chunked K
  __shared__ float Wt[64*128];
  __shared__ float sc[128], sh[128], ssum[128], ssq[128];
  int tid = threadIdx.x;
  int r0 = blockIdx.x * 64;
  if (tid < 128){ sc[tid]=stats[512+tid]; sh[tid]=stats[640+tid]; ssum[tid]=0.f; ssq[tid]=0.f; }
  int row = tid >> 2, sub = tid & 3, tx = tid & 15, ty = tid >> 4;
  float acc[4][8];
  #pragma unroll
  for (int i=0;i<4;i++)
    #pragma unroll
    for (int j=0;j<8;j++) acc[i][j] = 0.f;
  for (int kc=0; kc<128; kc+=64){
    __syncthreads();
    {
      const uint2* hp = (const uint2*)(h1 + (size_t)(r0+row)*128 + kc + sub*16);
      #pragma unroll
      for (int j2=0;j2<4;j2++){
        uint2 u = hp[j2];
        int cl = sub*16 + j2*4, cg = kc + cl;
        float f0=bflo(u.x), f1=bfhi(u.x), f2=bflo(u.y), f3=bfhi(u.y);
        At[(cl+0)*64+row] = fmaxf(fmaf(f0, sc[cg+0], sh[cg+0]), 0.f);
        At[(cl+1)*64+row] = fmaxf(fmaf(f1, sc[cg+1], sh[cg+1]), 0.f);
        At[(cl+2)*64+row] = fmaxf(fmaf(f2, sc[cg+2], sh[cg+2]), 0.f);
        At[(cl+3)*64+row] = fmaxf(fmaf(f3, sc[cg+3], sh[cg+3]), 0.f);
      }
    }
    {
      int o = tid >> 1, ch = tid & 1;
      const float* wr = w2 + (size_t)o*128 + kc + ch*32;
      #pragma unroll
      for (int j=0;j<8;j++){
        float4 v = *(const float4*)(wr + j*4);
        int c = ch*32 + j*4;
        Wt[(c+0)*128+o]=v.x; Wt[(c+1)*128+o]=v.y; Wt[(c+2)*128+o]=v.z; Wt[(c+3)*128+o]=v.w;
      }
    }
    __syncthreads();
    for (int c=0;c<64;c++){
      float4 a  = *(const float4*)(At + c*64 + ty*4);
      float4 b0 = *(const float4*)(Wt + c*128 + tx*4);
      float4 b1 = *(const float4*)(Wt + c*128 + 64 + tx*4);
      float ar[4] = {a.x, a.y, a.z, a.w};
      #pragma unroll
      for (int i=0;i<4;i++){
        acc[i][0]=fmaf(ar[i],b0.x,acc[i][0]); acc[i][1]=fmaf(ar[i],b0.y,acc[i][1]);
        acc[i][2]=fmaf(ar[i],b0.z,acc[i][2]); acc[i][3]=fmaf(ar[i],b0.w,acc[i][3]);
        acc[i][4]=fmaf(ar[i],b1.x,acc[i][4]); acc[i][5]=fmaf(ar[i],b1.y,acc[i][5]);
        acc[i][6]=fmaf(ar[i],b1.z,acc[i][6]); acc[i][7]=fmaf(ar[i],b1.w,acc[i][7]);
      }
    }
  }
  float* statsBase = (float*)stats;    // const-cast for atomics (region is writable ws)
  #pragma unroll
  for (int i=0;i<4;i++){
    size_t rr = (size_t)(r0 + ty*4 + i);
    uint2 u0, u1;
    u0.x = f2bf_pk(acc[i][0], acc[i][1]); u0.y = f2bf_pk(acc[i][2], acc[i][3]);
    u1.x = f2bf_pk(acc[i][4], acc[i][5]); u1.y = f2bf_pk(acc[i][6], acc[i][7]);
    *(uint2*)(h2 + rr*128 + tx*4)      = u0;
    *(uint2*)(h2 + rr*128 + 64 + tx*4) = u1;
  }
  #pragma unroll
  for (int j=0;j<8;j++){
    int col = (j<4) ? (tx*4+j) : (64 + tx*4 + (j-4));
    float s  = acc[0][j]+acc[1][j]+acc[2][j]+acc[3][j];
    float q2 = acc[0][j]*acc[0][j] + acc[1][j]*acc[1][j] + acc[2][j]*acc[2][j] + acc[3][j]*acc[3][j];
    atomicAdd(&ssum[col], s); atomicAdd(&ssq[col], q2);
  }
  __syncthreads();
  if (tid < 128){ atomicAdd(&statsBase[256+tid], ssum[tid]); atomicAdd(&statsBase[384+tid], ssq[tid]); }
}

// ---------- K8: bn2+relu+maxpool over k, transposed coalesced write ----------
__global__ __launch_bounds__(256) void k_pool(const __hip_bfloat16* __restrict__ h2,
                                              const float* __restrict__ stats, float* __restrict__ out1){
  __shared__ float ot[128*65];
  __shared__ float scs[128], shs[128];
  int tid = threadIdx.x, blk = blockIdx.x;
  int b = blk >> 4, m0 = (blk & 15) * 64;
  if (tid < 128){ scs[tid]=stats[768+tid]; shs[tid]=stats[896+tid]; }
  __syncthreads();
  int ml = tid >> 2, oq = tid & 3, o0 = oq*32;
  float scr[32], shr[32], mx[32];
  #pragma unroll
  for (int j=0;j<32;j++){ scr[j]=scs[o0+j]; shr[j]=shs[o0+j]; mx[j]=0.f; }   // relu>=0 so 0-init ok
  size_t rbase = ((size_t)(b*MM + m0 + ml))*16;
  for (int k=0;k<16;k++){
    const uint2* hp = (const uint2*)(h2 + (rbase+k)*128 + o0);
    #pragma unroll
    for (int j2=0;j2<8;j2++){
      uint2 u = hp[j2]; int j = j2*4;
      float f0=bflo(u.x), f1=bfhi(u.x), f2=bflo(u.y), f3=bfhi(u.y);
      mx[j+0] = fmaxf(mx[j+0], fmaxf(fmaf(f0, scr[j+0], shr[j+0]), 0.f));
      mx[j+1] = fmaxf(mx[j+1], fmaxf(fmaf(f1, scr[j+1], shr[j+1]), 0.f));
      mx[j+2] = fmaxf(mx[j+2], fmaxf(fmaf(f2, scr[j+2], shr[j+2]), 0.f));
      mx[j+3] = fmaxf(mx[j+3], fmaxf(fmaf(f3, scr[j+3], shr[j+3]), 0.f));
    }
  }
  #pragma unroll
  for (int j=0;j<32;j++) ot[(o0+j)*65 + ml] = mx[j];
  __syncthreads();
  int o = tid >> 1, mh = tid & 1;
  float* dst = out1 + ((size_t)(b*COUT + o))*MM + m0 + mh*32;
  #pragma unroll
  for (int j2=0;j2<8;j2++){
    float4 v;
    v.x=ot[o*65+mh*32+j2*4+0]; v.y=ot[o*65+mh*32+j2*4+1];
    v.z=ot[o*65+mh*32+j2*4+2]; v.w=ot[o*65+mh*32+j2*4+3];
    *(float4*)(dst + j2*4) = v;
  }
}

extern "C" void kernel_launch(void* const* d_in, const int* in_sizes, int n_in,
                              void* d_out, int out_size, void* d_ws, size_t ws_size,
                              hipStream_t stream) {
  (void)in_sizes; (void)n_in; (void)out_size; (void)ws_size;
  const float* p1 = (const float*)d_in[0];
  const float* x1 = (const float*)d_in[1];
  const float* w1 = (const float*)d_in[2];
  const float* g1 = (const float*)d_in[3];
  const float* b1 = (const float*)d_in[4];
  const float* w2 = (const float*)d_in[5];
  const float* g2 = (const float*)d_in[6];
  const float* b2 = (const float*)d_in[7];
  float* out = (float*)d_out;
  float* ws  = (float*)d_ws;

  // ws layout (float indices); total ~152.6 MB
  float* xt    = ws;                                   // 4,194,304 f
  int*   iknn  = (int*)(ws + 4194304);                 //   262,144 i
  float* p2w   = ws + 4456448;                         //    65,536 f  [B,M,4] xyz+|q|^2
  float* n1    = ws + 4521984;                         //    65,536 f
  float* stats = ws + 4587520;                         //     1,024 f
  __hip_bfloat16* h1 = (__hip_bfloat16*)(ws + 4588544);    // 33,554,432 bf16
  __hip_bfloat16* h2 = (__hip_bfloat16*)(ws + 21365760);   // 33,554,432 bf16

  float* outp2 = out;            // [B,M,3]
  float* out1  = out + 49152;    // [B,128,M]

  hipMemsetAsync(stats, 0, 512*sizeof(float), stream);
  k_transpose<<<BB*64, 256, 0, stream>>>(x1, xt);
  k_norms<<<256, 256, 0, stream>>>(p1, n1);
  k_fps<<<BB, 256, 0, stream>>>(p1, outp2, p2w);
  k_knn<<<4096, 256, 0, stream>>>(p1, n1, p2w, iknn);
  k_gemm1<<<4096, 256, 0, stream>>>(xt, iknn, p1, p2w, w1, h1, stats);
  k_fin<<<1, 128, 0, stream>>>(g1, b1, stats, 0, 512);
  k_gemm2<<<4096, 256, 0, stream>>>(h1, w2, stats, h2);
  k_fin<<<1, 128, 0, stream>>>(g2, b2, stats, 256, 768);
  k_pool<<<256, 256, 0, stream>>>(h2, stats, out1);
}

// Round 4
// 1488.356 us; speedup vs baseline: 1.2185x; 1.2185x over previous
//
#include <hip/hip_runtime.h>
#include <hip/hip_bf16.h>
#include <cstdint>

// Problem constants
#define BB 16
#define NN 4096
#define MM 1024
#define KNB 16
#define CIN 64
#define COUT 128
#define RTOT (BB*MM*KNB)   // 262144 rows
#define APAD 136           // padded bf16 row (128+8) for LDS MFMA tiles

typedef __attribute__((ext_vector_type(8))) short short8v;
typedef __attribute__((ext_vector_type(4))) float floatx4;

// ---------- helpers ----------
__device__ __forceinline__ float bflo(uint32_t u){ return __uint_as_float(u << 16); }
__device__ __forceinline__ float bfhi(uint32_t u){ return __uint_as_float(u & 0xffff0000u); }
__device__ __forceinline__ uint32_t f2bf_pk(float a, float b){
  uint32_t ua = __float_as_uint(a), ub = __float_as_uint(b);
  ua += 0x7fffu + ((ua >> 16) & 1u);   // RNE
  ub += 0x7fffu + ((ub >> 16) & 1u);
  return (ua >> 16) | (ub & 0xffff0000u);
}

// ---------- K0a: transpose x1 [B,64,N] -> xt [B,N,64] ----------
__global__ __launch_bounds__(256) void k_transpose(const float* __restrict__ x1, float* __restrict__ xt){
  __shared__ float t[64][65];
  int b = blockIdx.x >> 6, nt = blockIdx.x & 63;
  int n0 = nt*64, tid = threadIdx.x;
  int c = tid>>2, q = tid&3;
  const float* src = x1 + ((size_t)(b*64 + c))*NN + n0 + q*16;
  #pragma unroll
  for (int j=0;j<4;j++){
    float4 f = *(const float4*)(src + j*4);
    t[c][q*16+j*4+0]=f.x; t[c][q*16+j*4+1]=f.y; t[c][q*16+j*4+2]=f.z; t[c][q*16+j*4+3]=f.w;
  }
  __syncthreads();
  int n = tid>>2, c0 = q*16;
  float* dst = xt + ((size_t)(b*NN + n0 + n))*64 + c0;
  #pragma unroll
  for (int j=0;j<4;j++){
    float4 o;
    o.x=t[c0+j*4+0][n]; o.y=t[c0+j*4+1][n]; o.z=t[c0+j*4+2][n]; o.w=t[c0+j*4+3][n];
    *(float4*)(dst + j*4) = o;
  }
}

// ---------- K0b: n1[i] = |p|^2 (np op order, plain ops) ----------
__global__ __launch_bounds__(256) void k_norms(const float* __restrict__ p1, float* __restrict__ n1){
  int i = blockIdx.x*256 + threadIdx.x;      // < B*N = 65536
  float x = p1[(size_t)i*3+0], y = p1[(size_t)i*3+1], z = p1[(size_t)i*3+2];
  n1[i] = __fadd_rn(__fadd_rn(__fmul_rn(x,x),__fmul_rn(y,y)),__fmul_rn(z,z));
}

// ---------- K1: farthest point sampling v4 ----------
// v2's 512-thread / 8-pts-per-lane config (2 waves/SIMD: issue hides under chain
// stalls — v3's 1-wave/SIMD config regressed) + v3's mechanics (no per-iter global
// stores, DPP row-16 reduce, tournament argmax) + fold-merge of 32 candidates.
// Selection semantics bit-identical to numpy (np-order distance arithmetic,
// index-ordered merges, strict > so ties keep the lower index).
__global__ __launch_bounds__(512) void k_fps(const float* __restrict__ p1,
                                             float* __restrict__ outp2, float* __restrict__ p2w){
  __shared__ float pc[NN*3];          // 48 KB point coords
  __shared__ float4 sel[MM];          // 16 KB selected centroids
  __shared__ float2 cand[2][32];      // double-buffered row-16 winners (8 waves x 4 rows)
  int b = blockIdx.x, tid = threadIdx.x;
  int lane = tid & 63, wid = tid >> 6;
  const float* pb = p1 + (size_t)b*NN*3;
  float4 f[6];
  const float4* src = (const float4*)(pb + tid*24);
  #pragma unroll
  for (int j=0;j<6;j++) f[j] = src[j];
  float4* lp = (float4*)(pc + tid*24);
  #pragma unroll
  for (int j=0;j<6;j++) lp[j] = f[j];
  const float* fa = (const float*)f;
  float px[8],py[8],pz[8],dist[8];
  #pragma unroll
  for (int j=0;j<8;j++){ px[j]=fa[3*j]; py[j]=fa[3*j+1]; pz[j]=fa[3*j+2]; dist[j]=1e10f; }
  __syncthreads();
  float cx = pc[0], cy = pc[1], cz = pc[2];
  if (tid==0) sel[0] = make_float4(cx, cy, cz, 0.f);
  int g0 = tid*8;

  #define DPP_STEP(ctrl) { \
    int ov_i = __builtin_amdgcn_update_dpp(__float_as_int(mval), __float_as_int(mval), (ctrl), 0xf, 0xf, false); \
    int oi   = __builtin_amdgcn_update_dpp(midx, midx, (ctrl), 0xf, 0xf, false); \
    float ov = __int_as_float(ov_i); \
    if (ov > mval || (ov == mval && oi < midx)){ mval = ov; midx = oi; } }

  for (int i=1;i<MM;i++){
    float nd[8];
    #pragma unroll
    for (int j=0;j<8;j++){
      float dx=__fsub_rn(px[j],cx), dy=__fsub_rn(py[j],cy), dz=__fsub_rn(pz[j],cz);
      float d = __fadd_rn(__fadd_rn(__fmul_rn(dx,dx),__fmul_rn(dy,dy)),__fmul_rn(dz,dz));
      nd[j] = fminf(dist[j], d); dist[j] = nd[j];
    }
    // per-lane argmax: index-ordered tournament depth 3 (left wins ties)
    float tv[4]; int ti[4];
    #pragma unroll
    for (int j=0;j<4;j++){
      bool r = nd[2*j+1] > nd[2*j];
      tv[j] = r ? nd[2*j+1] : nd[2*j];
      ti[j] = g0 + 2*j + (r ? 1 : 0);
    }
    { bool r = tv[1] > tv[0]; tv[0] = r?tv[1]:tv[0]; ti[0] = r?ti[1]:ti[0]; }
    { bool r = tv[3] > tv[2]; tv[2] = r?tv[3]:tv[2]; ti[2] = r?ti[3]:ti[2]; }
    bool rr = tv[2] > tv[0];
    float mval = rr ? tv[2] : tv[0];
    int   midx = rr ? ti[2] : ti[0];
    // row-16 reduce via DPP
    DPP_STEP(0xB1); DPP_STEP(0x4E); DPP_STEP(0x124); DPP_STEP(0x128);
    int pbuf = i & 1;
    if ((lane & 15) == 0) cand[pbuf][wid*4 + (lane>>4)] = make_float2(mval, __int_as_float(midx));
    __syncthreads();
    // fold 32 candidates: local merge of slot s and s+16 (s lower -> ties keep lower idx),
    // then 4 DPP steps over the 16 remaining (replicated per row-16)
    float2 c0 = cand[pbuf][lane & 15];
    float2 c1 = cand[pbuf][16 + (lane & 15)];
    mval = c0.x; midx = __float_as_int(c0.y);
    { float v1 = c1.x; int i1 = __float_as_int(c1.y);
      if (v1 > mval){ mval = v1; midx = i1; } }
    DPP_STEP(0xB1); DPP_STEP(0x4E); DPP_STEP(0x124); DPP_STEP(0x128);
    cx = pc[midx*3+0]; cy = pc[midx*3+1]; cz = pc[midx*3+2];
    if (tid==0) sel[i] = make_float4(cx, cy, cz, 0.f);
  }
  #undef DPP_STEP
  __syncthreads();
  for (int e = tid; e < MM; e += 512){
    float4 s = sel[e];
    float n2 = __fadd_rn(__fadd_rn(__fmul_rn(s.x,s.x),__fmul_rn(s.y,s.y)),__fmul_rn(s.z,s.z));
    float* o = outp2 + ((size_t)b*MM + e)*3;
    o[0]=s.x; o[1]=s.y; o[2]=s.z;
    *(float4*)(p2w + ((size_t)b*MM + e)*4) = make_float4(s.x, s.y, s.z, n2);
  }
}

// ---------- K2: kNN, one wave per query ----------
__global__ __launch_bounds__(256) void k_knn(const float* __restrict__ p1, const float* __restrict__ n1,
                                             const float* __restrict__ p2w, int* __restrict__ iknn){
  int tid = threadIdx.x, lane = tid & 63, w = tid >> 6;
  int q = blockIdx.x*4 + w;
  int b = q >> 10;
  const float4 qv = *(const float4*)(p2w + (size_t)q*4);   // x,y,z,|q|^2
  const float* pb = p1 + (size_t)b*NN*3;
  const float* nb = n1 + (size_t)b*NN;
  float bd[16]; int bi[16];
  #pragma unroll
  for (int s=0;s<16;s++){ bd[s] = 1e30f; bi[s] = 0; }
  float wv = 1e30f; int wslot = 0;
  for (int t=0;t<64;t++){
    int c = t*64 + lane;
    float x = pb[(size_t)c*3+0], y = pb[(size_t)c*3+1], z = pb[(size_t)c*3+2];
    float nn = nb[c];
    float dot = fmaf(qv.z, z, fmaf(qv.y, y, __fmul_rn(qv.x, x)));
    float d2 = __fsub_rn(__fadd_rn(qv.w, nn), __fmul_rn(2.0f, dot));
    if (d2 < wv){
      #pragma unroll
      for (int s=0;s<16;s++) if (s==wslot){ bd[s]=d2; bi[s]=c; }
      wv = bd[0]; wslot = 0;
      #pragma unroll
      for (int s=1;s<16;s++) if (bd[s] > wv){ wv = bd[s]; wslot = s; }
    }
  }
  float lv = bd[0]; int ls = 0;
  #pragma unroll
  for (int s=1;s<16;s++) if (bd[s] < lv){ lv = bd[s]; ls = s; }
  for (int r=0;r<16;r++){
    float rv = lv; int rl = lane;
    #pragma unroll
    for (int off=32; off>=1; off>>=1){
      float ov = __shfl_xor(rv, off); int ol = __shfl_xor(rl, off);
      if (ov < rv || (ov == rv && ol < rl)){ rv = ov; rl = ol; }
    }
    if (lane == rl){
      int idx = 0;
      #pragma unroll
      for (int s=0;s<16;s++) if (s==ls) idx = bi[s];
      iknn[(size_t)q*16 + r] = idx;
      #pragma unroll
      for (int s=0;s<16;s++) if (s==ls) bd[s] = 1e30f;
      lv = bd[0]; ls = 0;
      #pragma unroll
      for (int s=1;s<16;s++) if (bd[s] < lv){ lv = bd[s]; ls = s; }
    }
  }
}

// ---------- K4: GEMM1 fp32 (fused gather) + spread stats, h1 out (bf16) ----------
__global__ __launch_bounds__(256) void k_gemm1(const float* __restrict__ xt, const int* __restrict__ iknn,
                                               const float* __restrict__ p1, const float* __restrict__ p2w,
                                               const float* __restrict__ w1,
                                               __hip_bfloat16* __restrict__ h1, float* __restrict__ S1){
  __shared__ float At[68*64];
  __shared__ float Wt[67*128];
  __shared__ float ssum[128], ssq[128];
  int tid = threadIdx.x;
  int r0 = blockIdx.x * 64;
  int b = r0 >> 14;
  for (int e = tid; e < 8576; e += 256){
    int o = e / 67; int c = e - o*67;
    Wt[c*128 + o] = w1[e];
  }
  if (tid < 128){ ssum[tid] = 0.f; ssq[tid] = 0.f; }
  int row = tid >> 2, sub = tid & 3;
  {
    int r = r0 + row;
    int n = iknn[r];
    int mg = r >> 4;
    const float* xr = xt + ((size_t)(b*NN + n))*64 + sub*16;
    #pragma unroll
    for (int j=0;j<4;j++){
      float4 v = *(const float4*)(xr + j*4);
      int cb = 3 + sub*16 + j*4;
      At[(cb+0)*64+row]=v.x; At[(cb+1)*64+row]=v.y; At[(cb+2)*64+row]=v.z; At[(cb+3)*64+row]=v.w;
    }
    if (sub==0){
      const float* pp = p1 + ((size_t)(b*NN + n))*3;
      const float* qq = p2w + (size_t)mg*4;
      At[0*64+row] = __fsub_rn(pp[0], qq[0]);
      At[1*64+row] = __fsub_rn(pp[1], qq[1]);
      At[2*64+row] = __fsub_rn(pp[2], qq[2]);
    }
  }
  __syncthreads();
  int tx = tid & 15, ty = tid >> 4;
  float acc[4][8];
  #pragma unroll
  for (int i=0;i<4;i++)
    #pragma unroll
    for (int j=0;j<8;j++) acc[i][j] = 0.f;
  for (int c=0;c<67;c++){
    float4 a  = *(const float4*)(At + c*64 + ty*4);
    float4 b0 = *(const float4*)(Wt + c*128 + tx*4);
    float4 b1 = *(const float4*)(Wt + c*128 + 64 + tx*4);
    float ar[4] = {a.x, a.y, a.z, a.w};
    #pragma unroll
    for (int i=0;i<4;i++){
      acc[i][0]=fmaf(ar[i],b0.x,acc[i][0]); acc[i][1]=fmaf(ar[i],b0.y,acc[i][1]);
      acc[i][2]=fmaf(ar[i],b0.z,acc[i][2]); acc[i][3]=fmaf(ar[i],b0.w,acc[i][3]);
      acc[i][4]=fmaf(ar[i],b1.x,acc[i][4]); acc[i][5]=fmaf(ar[i],b1.y,acc[i][5]);
      acc[i][6]=fmaf(ar[i],b1.z,acc[i][6]); acc[i][7]=fmaf(ar[i],b1.w,acc[i][7]);
    }
  }
  #pragma unroll
  for (int i=0;i<4;i++){
    size_t rr = (size_t)(r0 + ty*4 + i);
    uint2 u0, u1;
    u0.x = f2bf_pk(acc[i][0], acc[i][1]); u0.y = f2bf_pk(acc[i][2], acc[i][3]);
    u1.x = f2bf_pk(acc[i][4], acc[i][5]); u1.y = f2bf_pk(acc[i][6], acc[i][7]);
    *(uint2*)(h1 + rr*128 + tx*4)      = u0;
    *(uint2*)(h1 + rr*128 + 64 + tx*4) = u1;
  }
  #pragma unroll
  for (int j=0;j<8;j++){
    int col = (j<4) ? (tx*4+j) : (64 + tx*4 + (j-4));
    float s  = acc[0][j]+acc[1][j]+acc[2][j]+acc[3][j];
    float q2 = acc[0][j]*acc[0][j] + acc[1][j]*acc[1][j] + acc[2][j]*acc[2][j] + acc[3][j]*acc[3][j];
    atomicAdd(&ssum[col], s); atomicAdd(&ssq[col], q2);
  }
  __syncthreads();
  int cp = (blockIdx.x & 31)*256;
  if (tid < 128){ atomicAdd(&S1[cp+tid], ssum[tid]); atomicAdd(&S1[cp+128+tid], ssq[tid]); }
}

// ---------- K5/K7: finalize BN scale/shift from 32 spread copies ----------
__global__ void k_fin(const float* __restrict__ g, const float* __restrict__ bbias,
                      const float* __restrict__ S, float* __restrict__ P){
  int o = threadIdx.x;
  float s=0.f, q=0.f;
  for (int c=0;c<32;c++){ s += S[c*256+o]; q += S[c*256+128+o]; }
  float inv = 1.0f / (float)RTOT;
  float mean = s * inv;
  float var  = q * inv - mean*mean;
  float rs = 1.0f / sqrtf(var + 1e-5f);
  float scv = g[o] * rs;
  P[o]     = scv;
  P[128+o] = bbias[o] - mean*scv;
}

// ---------- K6: GEMM2 via bf16 MFMA (bn1+relu fused on A-stage) ----------
__global__ __launch_bounds__(256) void k_gemm2(const __hip_bfloat16* __restrict__ h1,
                                               const float* __restrict__ w2,
                                               const float* __restrict__ P1,
                                               float* __restrict__ S2,
                                               __hip_bfloat16* __restrict__ h2){
  __shared__ __hip_bfloat16 Ah[64*APAD];     // 17408 B, A tile (also reused for D)
  __shared__ __hip_bfloat16 Bh[128*APAD];    // 34816 B, B tile = bf16(w2)
  __shared__ float scb[128], shb[128];
  int tid = threadIdx.x;
  int r0 = blockIdx.x * 64;
  if (tid < 128){ scb[tid] = P1[tid]; shb[tid] = P1[128+tid]; }
  __syncthreads();
  // stage A: relu(bn1(h1)) -> bf16, rows r0..r0+63
  {
    int row = tid >> 2, seg = tid & 3;
    const uint4* hp4 = (const uint4*)(h1 + ((size_t)(r0+row))*128 + seg*32);
    #pragma unroll
    for (int q=0;q<4;q++){
      uint4 u = hp4[q];
      int cg = seg*32 + q*8;
      uint32_t wv[4] = {u.x,u.y,u.z,u.w};
      uint32_t ov[4];
      #pragma unroll
      for (int t=0;t<4;t++){
        int c = cg + t*2;
        float a0 = fmaxf(fmaf(bflo(wv[t]), scb[c],   shb[c]),   0.f);
        float a1 = fmaxf(fmaf(bfhi(wv[t]), scb[c+1], shb[c+1]), 0.f);
        ov[t] = f2bf_pk(a0, a1);
      }
      *(uint4*)(Ah + row*APAD + cg) = make_uint4(ov[0],ov[1],ov[2],ov[3]);
    }
  }
  // stage B: Bh[n][k] = bf16(w2[n][k])
  {
    int o = tid >> 1, hf = tid & 1;
    const float4* wr = (const float4*)(w2 + (size_t)o*128 + hf*64);
    uint32_t* bd = (uint32_t*)(Bh + o*APAD + hf*64);
    #pragma unroll
    for (int q=0;q<16;q++){
      float4 v = wr[q];
      bd[2*q]   = f2bf_pk(v.x, v.y);
      bd[2*q+1] = f2bf_pk(v.z, v.w);
    }
  }
  __syncthreads();
  int lane = tid & 63, wid = tid >> 6;
  int m0 = wid*16, ml = lane & 15, quad = lane >> 4;
  // A frags: A[m=lane&15][k=quad*8+j] (m89-verified layout)
  short8v af[4];
  #pragma unroll
  for (int kc=0;kc<4;kc++)
    af[kc] = *(const short8v*)(Ah + (m0+ml)*APAD + kc*32 + quad*8);
  floatx4 acc[8];
  #pragma unroll
  for (int ct=0;ct<8;ct++) acc[ct] = (floatx4){0.f,0.f,0.f,0.f};
  #pragma unroll
  for (int ct=0;ct<8;ct++){
    #pragma unroll
    for (int kc=0;kc<4;kc++){
      short8v bf = *(const short8v*)(Bh + (ct*16+ml)*APAD + kc*32 + quad*8);
      acc[ct] = __builtin_amdgcn_mfma_f32_16x16x32_bf16(af[kc], bf, acc[ct], 0, 0, 0);
    }
  }
  // D -> bf16 -> Ah (each wave overwrites only its own 16-row slice; per-wave DS
  // ordering guarantees its A-frag reads completed first)
  #pragma unroll
  for (int ct=0;ct<8;ct++){
    #pragma unroll
    for (int r=0;r<4;r++){
      uint32_t ub = __float_as_uint(acc[ct][r]);
      ub += 0x7fffu + ((ub>>16)&1u);
      ((uint16_t*)Ah)[(m0 + quad*4 + r)*APAD + ct*16 + ml] = (uint16_t)(ub>>16);
    }
  }
  __syncthreads();
  // coalesced global write of h2 tile
  {
    int row = tid >> 2, seg = tid & 3;
    uint4* dst = (uint4*)(h2 + ((size_t)(r0+row))*128 + seg*32);
    const uint4* srcp = (const uint4*)(Ah + row*APAD + seg*32);
    #pragma unroll
    for (int q=0;q<4;q++) dst[q] = srcp[q];
  }
  // stats for bn2 (from bf16-rounded h2 tile), spread copies
  {
    int col = tid & 127, hf2 = tid >> 7;
    float s=0.f, q=0.f;
    #pragma unroll
    for (int r=0;r<32;r++){
      uint16_t uv = ((const uint16_t*)Ah)[(hf2*32 + r)*APAD + col];
      float v = __uint_as_float(((uint32_t)uv)<<16);
      s += v; q += v*v;
    }
    int cp = (blockIdx.x & 31)*256;
    atomicAdd(&S2[cp + col], s);
    atomicAdd(&S2[cp + 128 + col], q);
  }
}

// ---------- K8: bn2+relu+maxpool over k, transposed coalesced write ----------
__global__ __launch_bounds__(256) void k_pool(const __hip_bfloat16* __restrict__ h2,
                                              const float* __restrict__ P2, float* __restrict__ out1){
  __shared__ float ot[128*65];
  __shared__ float scs[128], shs[128];
  int tid = threadIdx.x, blk = blockIdx.x;
  int b = blk >> 4, m0 = (blk & 15) * 64;
  if (tid < 128){ scs[tid]=P2[tid]; shs[tid]=P2[128+tid]; }
  __syncthreads();
  int ml = tid >> 2, oq = tid & 3, o0 = oq*32;
  float scr[32], shr[32], mx[32];
  #pragma unroll
  for (int j=0;j<32;j++){ scr[j]=scs[o0+j]; shr[j]=shs[o0+j]; mx[j]=0.f; }
  size_t rbase = ((size_t)(b*MM + m0 + ml))*16;
  for (int k=0;k<16;k++){
    const uint2* hp = (const uint2*)(h2 + (rbase+k)*128 + o0);
    #pragma unroll
    for (int j2=0;j2<8;j2++){
      uint2 u = hp[j2]; int j = j2*4;
      float f0=bflo(u.x), f1=bfhi(u.x), f2=bflo(u.y), f3=bfhi(u.y);
      mx[j+0] = fmaxf(mx[j+0], fmaxf(fmaf(f0, scr[j+0], shr[j+0]), 0.f));
      mx[j+1] = fmaxf(mx[j+1], fmaxf(fmaf(f1, scr[j+1], shr[j+1]), 0.f));
      mx[j+2] = fmaxf(mx[j+2], fmaxf(fmaf(f2, scr[j+2], shr[j+2]), 0.f));
      mx[j+3] = fmaxf(mx[j+3], fmaxf(fmaf(f3, scr[j+3], shr[j+3]), 0.f));
    }
  }
  #pragma unroll
  for (int j=0;j<32;j++) ot[(o0+j)*65 + ml] = mx[j];
  __syncthreads();
  int o = tid >> 1, mh = tid & 1;
  float* dst = out1 + ((size_t)(b*COUT + o))*MM + m0 + mh*32;
  #pragma unroll
  for (int j2=0;j2<8;j2++){
    float4 v;
    v.x=ot[o*65+mh*32+j2*4+0]; v.y=ot[o*65+mh*32+j2*4+1];
    v.z=ot[o*65+mh*32+j2*4+2]; v.w=ot[o*65+mh*32+j2*4+3];
    *(float4*)(dst + j2*4) = v;
  }
}

extern "C" void kernel_launch(void* const* d_in, const int* in_sizes, int n_in,
                              void* d_out, int out_size, void* d_ws, size_t ws_size,
                              hipStream_t stream) {
  (void)in_sizes; (void)n_in; (void)out_size; (void)ws_size;
  const float* p1 = (const float*)d_in[0];
  const float* x1 = (const float*)d_in[1];
  const float* w1 = (const float*)d_in[2];
  const float* g1 = (const float*)d_in[3];
  const float* b1 = (const float*)d_in[4];
  const float* w2 = (const float*)d_in[5];
  const float* g2 = (const float*)d_in[6];
  const float* b2 = (const float*)d_in[7];
  float* out = (float*)d_out;
  float* ws  = (float*)d_ws;

  // ws layout (float indices), total ~152.57 MB (same footprint as prior rounds).
  // Stat buffers overlap dead regions: S1+P live in n1's space (dead after knn,
  // memset between knn and gemm1); S2 lives in xt's space (dead after gemm1).
  float* xt    = ws;                                   // 4,194,304 f (dead after gemm1)
  float* S2    = ws;                                   //     8,192 f (gemm2 stat copies)
  int*   iknn  = (int*)(ws + 4194304);                 //   262,144 i
  float* p2w   = ws + 4456448;                         //    65,536 f [B,M,4]
  float* n1    = ws + 4521984;                         //    65,536 f (dead after knn)
  float* S1    = n1;                                   //     8,192 f (gemm1 stat copies)
  float* P1    = n1 + 8192;                            //       256 f bn1 scale/shift
  float* P2    = n1 + 8448;                            //       256 f bn2 scale/shift
  __hip_bfloat16* h1 = (__hip_bfloat16*)(ws + 4587520);    // 33,554,432 bf16
  __hip_bfloat16* h2 = (__hip_bfloat16*)(ws + 21364736);   // 33,554,432 bf16

  float* outp2 = out;            // [B,M,3]
  float* out1  = out + 49152;    // [B,128,M]

  k_transpose<<<BB*64, 256, 0, stream>>>(x1, xt);
  k_norms<<<256, 256, 0, stream>>>(p1, n1);
  k_fps<<<BB, 512, 0, stream>>>(p1, outp2, p2w);
  k_knn<<<4096, 256, 0, stream>>>(p1, n1, p2w, iknn);
  hipMemsetAsync(S1, 0, 8192*sizeof(float), stream);       // n1 dead from here
  k_gemm1<<<4096, 256, 0, stream>>>(xt, iknn, p1, p2w, w1, h1, S1);
  k_fin<<<1, 128, 0, stream>>>(g1, b1, S1, P1);
  hipMemsetAsync(S2, 0, 8192*sizeof(float), stream);       // xt dead from here
  k_gemm2<<<4096, 256, 0, stream>>>(h1, w2, P1, S2, h2);
  k_fin<<<1, 128, 0, stream>>>(g2, b2, S2, P2);
  k_pool<<<256, 256, 0, stream>>>(h2, P2, out1);
}

// Round 5
// 1431.921 us; speedup vs baseline: 1.2666x; 1.0394x over previous
//
#include <hip/hip_runtime.h>
#include <hip/hip_bf16.h>
#include <cstdint>

// Problem constants
#define BB 16
#define NN 4096
#define MM 1024
#define KNB 16
#define CIN 64
#define COUT 128
#define RTOT (BB*MM*KNB)   // 262144 rows
#define AP1 104            // gemm1 LDS row stride (96 used + 8 pad), bf16
#define AP2 136            // gemm2 LDS row stride (128 + 8 pad), bf16

typedef __attribute__((ext_vector_type(8))) short short8v;
typedef __attribute__((ext_vector_type(4))) float floatx4;

// ---------- helpers ----------
__device__ __forceinline__ float bflo(uint32_t u){ return __uint_as_float(u << 16); }
__device__ __forceinline__ float bfhi(uint32_t u){ return __uint_as_float(u & 0xffff0000u); }
__device__ __forceinline__ uint32_t f2bf_pk(float a, float b){
  uint32_t ua = __float_as_uint(a), ub = __float_as_uint(b);
  ua += 0x7fffu + ((ua >> 16) & 1u);   // RNE
  ub += 0x7fffu + ((ub >> 16) & 1u);
  return (ua >> 16) | (ub & 0xffff0000u);
}
__device__ __forceinline__ uint16_t f2bf1(float a){
  uint32_t u = __float_as_uint(a);
  u += 0x7fffu + ((u >> 16) & 1u);
  return (uint16_t)(u >> 16);
}

// ---------- K0a: transpose x1 [B,64,N] -> xtb [B,N,64] bf16 ----------
__global__ __launch_bounds__(256) void k_transpose(const float* __restrict__ x1, __hip_bfloat16* __restrict__ xtb){
  __shared__ float t[64][65];
  int b = blockIdx.x >> 6, nt = blockIdx.x & 63;
  int n0 = nt*64, tid = threadIdx.x;
  int c = tid>>2, q = tid&3;
  const float* src = x1 + ((size_t)(b*64 + c))*NN + n0 + q*16;
  #pragma unroll
  for (int j=0;j<4;j++){
    float4 f = *(const float4*)(src + j*4);
    t[c][q*16+j*4+0]=f.x; t[c][q*16+j*4+1]=f.y; t[c][q*16+j*4+2]=f.z; t[c][q*16+j*4+3]=f.w;
  }
  __syncthreads();
  int n = tid>>2, c0 = q*16;
  uint32_t* dst = (uint32_t*)(xtb + ((size_t)(b*NN + n0 + n))*64 + c0);
  #pragma unroll
  for (int j=0;j<8;j++)
    dst[j] = f2bf_pk(t[c0+2*j][n], t[c0+2*j+1][n]);
}

// ---------- K0b: p1n[i] = (x,y,z,|p|^2) (np op order for the norm) ----------
__global__ __launch_bounds__(256) void k_prep(const float* __restrict__ p1, float4* __restrict__ p1n){
  int i = blockIdx.x*256 + threadIdx.x;      // < B*N = 65536
  float x = p1[(size_t)i*3+0], y = p1[(size_t)i*3+1], z = p1[(size_t)i*3+2];
  float n = __fadd_rn(__fadd_rn(__fmul_rn(x,x),__fmul_rn(y,y)),__fmul_rn(z,z));
  p1n[i] = make_float4(x,y,z,n);
}

// ---------- K1: farthest point sampling v4 (unchanged from round 4) ----------
__global__ __launch_bounds__(512) void k_fps(const float* __restrict__ p1,
                                             float* __restrict__ outp2, float* __restrict__ p2w){
  __shared__ float pc[NN*3];
  __shared__ float4 sel[MM];
  __shared__ float2 cand[2][32];
  int b = blockIdx.x, tid = threadIdx.x;
  int lane = tid & 63, wid = tid >> 6;
  const float* pb = p1 + (size_t)b*NN*3;
  float4 f[6];
  const float4* src = (const float4*)(pb + tid*24);
  #pragma unroll
  for (int j=0;j<6;j++) f[j] = src[j];
  float4* lp = (float4*)(pc + tid*24);
  #pragma unroll
  for (int j=0;j<6;j++) lp[j] = f[j];
  const float* fa = (const float*)f;
  float px[8],py[8],pz[8],dist[8];
  #pragma unroll
  for (int j=0;j<8;j++){ px[j]=fa[3*j]; py[j]=fa[3*j+1]; pz[j]=fa[3*j+2]; dist[j]=1e10f; }
  __syncthreads();
  float cx = pc[0], cy = pc[1], cz = pc[2];
  if (tid==0) sel[0] = make_float4(cx, cy, cz, 0.f);
  int g0 = tid*8;

  #define DPP_STEP(ctrl) { \
    int ov_i = __builtin_amdgcn_update_dpp(__float_as_int(mval), __float_as_int(mval), (ctrl), 0xf, 0xf, false); \
    int oi   = __builtin_amdgcn_update_dpp(midx, midx, (ctrl), 0xf, 0xf, false); \
    float ov = __int_as_float(ov_i); \
    if (ov > mval || (ov == mval && oi < midx)){ mval = ov; midx = oi; } }

  for (int i=1;i<MM;i++){
    float nd[8];
    #pragma unroll
    for (int j=0;j<8;j++){
      float dx=__fsub_rn(px[j],cx), dy=__fsub_rn(py[j],cy), dz=__fsub_rn(pz[j],cz);
      float d = __fadd_rn(__fadd_rn(__fmul_rn(dx,dx),__fmul_rn(dy,dy)),__fmul_rn(dz,dz));
      nd[j] = fminf(dist[j], d); dist[j] = nd[j];
    }
    float tv[4]; int ti[4];
    #pragma unroll
    for (int j=0;j<4;j++){
      bool r = nd[2*j+1] > nd[2*j];
      tv[j] = r ? nd[2*j+1] : nd[2*j];
      ti[j] = g0 + 2*j + (r ? 1 : 0);
    }
    { bool r = tv[1] > tv[0]; tv[0] = r?tv[1]:tv[0]; ti[0] = r?ti[1]:ti[0]; }
    { bool r = tv[3] > tv[2]; tv[2] = r?tv[3]:tv[2]; ti[2] = r?ti[3]:ti[2]; }
    bool rr = tv[2] > tv[0];
    float mval = rr ? tv[2] : tv[0];
    int   midx = rr ? ti[2] : ti[0];
    DPP_STEP(0xB1); DPP_STEP(0x4E); DPP_STEP(0x124); DPP_STEP(0x128);
    int pbuf = i & 1;
    if ((lane & 15) == 0) cand[pbuf][wid*4 + (lane>>4)] = make_float2(mval, __int_as_float(midx));
    __syncthreads();
    float2 c0 = cand[pbuf][lane & 15];
    float2 c1 = cand[pbuf][16 + (lane & 15)];
    mval = c0.x; midx = __float_as_int(c0.y);
    { float v1 = c1.x; int i1 = __float_as_int(c1.y);
      if (v1 > mval){ mval = v1; midx = i1; } }
    DPP_STEP(0xB1); DPP_STEP(0x4E); DPP_STEP(0x124); DPP_STEP(0x128);
    cx = pc[midx*3+0]; cy = pc[midx*3+1]; cz = pc[midx*3+2];
    if (tid==0) sel[i] = make_float4(cx, cy, cz, 0.f);
  }
  #undef DPP_STEP
  __syncthreads();
  for (int e = tid; e < MM; e += 512){
    float4 s = sel[e];
    float n2 = __fadd_rn(__fadd_rn(__fmul_rn(s.x,s.x),__fmul_rn(s.y,s.y)),__fmul_rn(s.z,s.z));
    float* o = outp2 + ((size_t)b*MM + e)*3;
    o[0]=s.x; o[1]=s.y; o[2]=s.z;
    *(float4*)(p2w + ((size_t)b*MM + e)*4) = make_float4(s.x, s.y, s.z, n2);
  }
}

// ---------- K2: kNN, one wave per query; float4 candidate stream + prefetch ----------
__global__ __launch_bounds__(256) void k_knn(const float4* __restrict__ p1n,
                                             const float* __restrict__ p2w, int* __restrict__ iknn){
  int tid = threadIdx.x, lane = tid & 63, w = tid >> 6;
  int q = blockIdx.x*4 + w;
  int b = q >> 10;
  const float4 qv = *(const float4*)(p2w + (size_t)q*4);   // x,y,z,|q|^2
  const float4* pbn = p1n + (size_t)b*NN;
  float bd[16]; int bi[16];
  #pragma unroll
  for (int s=0;s<16;s++){ bd[s] = 1e30f; bi[s] = 0; }
  float wv = 1e30f; int wslot = 0;

  #define KPROC(T, PV) { \
    float dot = fmaf(qv.z, (PV).z, fmaf(qv.y, (PV).y, __fmul_rn(qv.x, (PV).x))); \
    float d2 = __fsub_rn(__fadd_rn(qv.w, (PV).w), __fmul_rn(2.0f, dot)); \
    if (d2 < wv){ \
      int c = (T)*64 + lane; \
      _Pragma("unroll") \
      for (int s=0;s<16;s++) if (s==wslot){ bd[s]=d2; bi[s]=c; } \
      wv = bd[0]; wslot = 0; \
      _Pragma("unroll") \
      for (int s=1;s<16;s++) if (bd[s] > wv){ wv = bd[s]; wslot = s; } \
    } }

  float4 cur = pbn[lane];
  for (int t=0;t<63;t++){
    float4 nx = pbn[(t+1)*64 + lane];
    KPROC(t, cur);
    cur = nx;
  }
  KPROC(63, cur);
  #undef KPROC

  float lv = bd[0]; int ls = 0;
  #pragma unroll
  for (int s=1;s<16;s++) if (bd[s] < lv){ lv = bd[s]; ls = s; }
  for (int r=0;r<16;r++){
    float rv = lv; int rl = lane;
    #pragma unroll
    for (int off=32; off>=1; off>>=1){
      float ov = __shfl_xor(rv, off); int ol = __shfl_xor(rl, off);
      if (ov < rv || (ov == rv && ol < rl)){ rv = ov; rl = ol; }
    }
    if (lane == rl){
      int idx = 0;
      #pragma unroll
      for (int s=0;s<16;s++) if (s==ls) idx = bi[s];
      iknn[(size_t)q*16 + r] = idx;
      #pragma unroll
      for (int s=0;s<16;s++) if (s==ls) bd[s] = 1e30f;
      lv = bd[0]; ls = 0;
      #pragma unroll
      for (int s=1;s<16;s++) if (bd[s] < lv){ lv = bd[s]; ls = s; }
    }
  }
}

// ---------- K4: GEMM1 via bf16 MFMA (fused gather), K permuted to [x(64)|rel(3)|0] ----------
__global__ __launch_bounds__(256) void k_gemm1(const __hip_bfloat16* __restrict__ xtb, const int* __restrict__ iknn,
                                               const float* __restrict__ p1, const float* __restrict__ p2w,
                                               const float* __restrict__ w1,
                                               __hip_bfloat16* __restrict__ h1, float* __restrict__ S1){
  __shared__ __hip_bfloat16 Ah[64*AP1];      // 13.3 KB
  __shared__ __hip_bfloat16 Bh[128*AP1];     // 26.6 KB
  __shared__ __hip_bfloat16 Dh[64*AP2];      // 17.4 KB
  __shared__ float ssum[128], ssq[128];
  int tid = threadIdx.x;
  int r0 = blockIdx.x * 64;
  int b = r0 >> 14;
  if (tid < 128){ ssum[tid]=0.f; ssq[tid]=0.f; }
  // stage B: Bh[o][k] = bf16( k<64 ? w1[o][3+k] : k<67 ? w1[o][k-64] : 0 )
  for (int e = tid; e < 128*96; e += 256){
    int o = e / 96, k = e - o*96;
    float v = (k < 64) ? w1[o*67 + 3 + k] : ((k < 67) ? w1[o*67 + (k-64)] : 0.f);
    ((uint16_t*)Bh)[o*AP1 + k] = f2bf1(v);
  }
  // stage A
  if (tid < 128){
    int row = tid >> 1, hf = tid & 1;
    int n = iknn[r0 + row];
    const uint4* s4 = (const uint4*)(xtb + ((size_t)(b*NN + n))*64 + hf*32);
    uint4* d4 = (uint4*)(Ah + row*AP1 + hf*32);
    #pragma unroll
    for (int j=0;j<4;j++) d4[j] = s4[j];
  } else {
    int t2 = tid - 128;
    int row = t2 >> 1, part = t2 & 1;
    uint4* d4 = (uint4*)(Ah + row*AP1 + 64 + part*16);
    if (part == 0){
      int r = r0 + row;
      int n = iknn[r];
      int mg = r >> 4;
      const float* pp = p1 + ((size_t)(b*NN + n))*3;
      const float* qq = p2w + (size_t)mg*4;
      float rx = __fsub_rn(pp[0], qq[0]);
      float ry = __fsub_rn(pp[1], qq[1]);
      float rz = __fsub_rn(pp[2], qq[2]);
      d4[0] = make_uint4(f2bf_pk(rx, ry), f2bf_pk(rz, 0.f), 0u, 0u);
      d4[1] = make_uint4(0u,0u,0u,0u);
    } else {
      d4[0] = make_uint4(0u,0u,0u,0u);
      d4[1] = make_uint4(0u,0u,0u,0u);
    }
  }
  __syncthreads();
  int lane = tid & 63, wid = tid >> 6;
  int m0 = wid*16, ml = lane & 15, quad = lane >> 4;
  short8v af[3];
  #pragma unroll
  for (int kc=0;kc<3;kc++)
    af[kc] = *(const short8v*)(Ah + (m0+ml)*AP1 + kc*32 + quad*8);
  floatx4 acc[8];
  #pragma unroll
  for (int ct=0;ct<8;ct++) acc[ct] = (floatx4){0.f,0.f,0.f,0.f};
  #pragma unroll
  for (int ct=0;ct<8;ct++){
    #pragma unroll
    for (int kc=0;kc<3;kc++){
      short8v bf = *(const short8v*)(Bh + (ct*16+ml)*AP1 + kc*32 + quad*8);
      acc[ct] = __builtin_amdgcn_mfma_f32_16x16x32_bf16(af[kc], bf, acc[ct], 0, 0, 0);
    }
  }
  // epilogue: D->bf16 Dh tile; stats via cross-quad shuffle reduce
  float csum[8], csq[8];
  #pragma unroll
  for (int ct=0;ct<8;ct++){
    float a0=acc[ct][0], a1=acc[ct][1], a2=acc[ct][2], a3=acc[ct][3];
    float s = (a0+a1)+(a2+a3);
    float qq2 = (a0*a0+a1*a1)+(a2*a2+a3*a3);
    s += __shfl_xor(s,16);  s += __shfl_xor(s,32);
    qq2 += __shfl_xor(qq2,16); qq2 += __shfl_xor(qq2,32);
    csum[ct]=s; csq[ct]=qq2;
    #pragma unroll
    for (int r=0;r<4;r++)
      ((uint16_t*)Dh)[(m0 + quad*4 + r)*AP2 + ct*16 + ml] = f2bf1(acc[ct][r]);
  }
  #pragma unroll
  for (int j=0;j<2;j++){
    int ct = quad*2 + j, col = ct*16 + ml;
    atomicAdd(&ssum[col], csum[ct]);
    atomicAdd(&ssq[col],  csq[ct]);
  }
  __syncthreads();
  {
    int row = tid >> 2, seg = tid & 3;
    uint4* dst = (uint4*)(h1 + ((size_t)(r0+row))*128 + seg*32);
    const uint4* s4 = (const uint4*)(Dh + row*AP2 + seg*32);
    #pragma unroll
    for (int q2=0;q2<4;q2++) dst[q2] = s4[q2];
  }
  int cp = (blockIdx.x & 31)*256;
  if (tid < 128){ atomicAdd(&S1[cp+tid], ssum[tid]); atomicAdd(&S1[cp+128+tid], ssq[tid]); }
}

// ---------- K5/K7: finalize BN scale/shift from 32 spread copies ----------
__global__ void k_fin(const float* __restrict__ g, const float* __restrict__ bbias,
                      const float* __restrict__ S, float* __restrict__ P){
  int o = threadIdx.x;
  float s=0.f, q=0.f;
  for (int c=0;c<32;c++){ s += S[c*256+o]; q += S[c*256+128+o]; }
  float inv = 1.0f / (float)RTOT;
  float mean = s * inv;
  float var  = q * inv - mean*mean;
  float rs = 1.0f / sqrtf(var + 1e-5f);
  float scv = g[o] * rs;
  P[o]     = scv;
  P[128+o] = bbias[o] - mean*scv;
}

// ---------- K6: GEMM2 bf16 MFMA; epilogue = fused k-maxpool (hmax/hmin) + stats ----------
// max_k relu(sc*h+sh) == relu(sc*hmax+sh) for sc>=0, relu(sc*hmin+sh) for sc<0
// (monotone per-channel affine; exact same selected element). h2 never materialized.
__global__ __launch_bounds__(256) void k_gemm2(const __hip_bfloat16* __restrict__ h1,
                                               const float* __restrict__ w2,
                                               const float* __restrict__ P1,
                                               float* __restrict__ S2,
                                               float* __restrict__ hmax, float* __restrict__ hmin){
  __shared__ __hip_bfloat16 Ah[64*AP2];      // 17.4 KB
  __shared__ __hip_bfloat16 Bh[128*AP2];     // 34.8 KB
  __shared__ float scb[128], shb[128], ssum[128], ssq[128];
  int tid = threadIdx.x;
  int r0 = blockIdx.x * 64;
  if (tid < 128){ scb[tid] = P1[tid]; shb[tid] = P1[128+tid]; ssum[tid]=0.f; ssq[tid]=0.f; }
  __syncthreads();
  // stage A: relu(bn1(h1)) -> bf16
  {
    int row = tid >> 2, seg = tid & 3;
    const uint4* hp4 = (const uint4*)(h1 + ((size_t)(r0+row))*128 + seg*32);
    #pragma unroll
    for (int q=0;q<4;q++){
      uint4 u = hp4[q];
      int cg = seg*32 + q*8;
      uint32_t wv[4] = {u.x,u.y,u.z,u.w};
      uint32_t ov[4];
      #pragma unroll
      for (int t=0;t<4;t++){
        int c = cg + t*2;
        float a0 = fmaxf(fmaf(bflo(wv[t]), scb[c],   shb[c]),   0.f);
        float a1 = fmaxf(fmaf(bfhi(wv[t]), scb[c+1], shb[c+1]), 0.f);
        ov[t] = f2bf_pk(a0, a1);
      }
      *(uint4*)(Ah + row*AP2 + cg) = make_uint4(ov[0],ov[1],ov[2],ov[3]);
    }
  }
  // stage B: Bh[n][k] = bf16(w2[n][k])
  {
    int o = tid >> 1, hf = tid & 1;
    const float4* wr = (const float4*)(w2 + (size_t)o*128 + hf*64);
    uint32_t* bd = (uint32_t*)(Bh + o*AP2 + hf*64);
    #pragma unroll
    for (int q=0;q<16;q++){
      float4 v = wr[q];
      bd[2*q]   = f2bf_pk(v.x, v.y);
      bd[2*q+1] = f2bf_pk(v.z, v.w);
    }
  }
  __syncthreads();
  int lane = tid & 63, wid = tid >> 6;
  int m0 = wid*16, ml = lane & 15, quad = lane >> 4;
  short8v af[4];
  #pragma unroll
  for (int kc=0;kc<4;kc++)
    af[kc] = *(const short8v*)(Ah + (m0+ml)*AP2 + kc*32 + quad*8);
  floatx4 acc[8];
  #pragma unroll
  for (int ct=0;ct<8;ct++) acc[ct] = (floatx4){0.f,0.f,0.f,0.f};
  #pragma unroll
  for (int ct=0;ct<8;ct++){
    #pragma unroll
    for (int kc=0;kc<4;kc++){
      short8v bf = *(const short8v*)(Bh + (ct*16+ml)*AP2 + kc*32 + quad*8);
      acc[ct] = __builtin_amdgcn_mfma_f32_16x16x32_bf16(af[kc], bf, acc[ct], 0, 0, 0);
    }
  }
  // epilogue: wave's 16 rows = one m-group's 16 neighbors -> max/min over k + stats
  int mrow = (r0 >> 4) + wid;                 // global b*M+m
  float cm[8], cn[8], cs[8], cq[8];
  #pragma unroll
  for (int ct=0;ct<8;ct++){
    float a0=acc[ct][0], a1=acc[ct][1], a2=acc[ct][2], a3=acc[ct][3];
    float mx = fmaxf(fmaxf(a0,a1), fmaxf(a2,a3));
    float mn = fminf(fminf(a0,a1), fminf(a2,a3));
    float s  = (a0+a1)+(a2+a3);
    float q2 = (a0*a0+a1*a1)+(a2*a2+a3*a3);
    mx = fmaxf(mx, __shfl_xor(mx,16)); mx = fmaxf(mx, __shfl_xor(mx,32));
    mn = fminf(mn, __shfl_xor(mn,16)); mn = fminf(mn, __shfl_xor(mn,32));
    s += __shfl_xor(s,16);  s += __shfl_xor(s,32);
    q2 += __shfl_xor(q2,16); q2 += __shfl_xor(q2,32);
    cm[ct]=mx; cn[ct]=mn; cs[ct]=s; cq[ct]=q2;
  }
  #pragma unroll
  for (int j=0;j<2;j++){
    int ct = quad*2 + j, col = ct*16 + ml;
    hmax[(size_t)mrow*128 + col] = cm[ct];
    hmin[(size_t)mrow*128 + col] = cn[ct];
    atomicAdd(&ssum[col], cs[ct]);
    atomicAdd(&ssq[col],  cq[ct]);
  }
  __syncthreads();
  int cp = (blockIdx.x & 31)*256;
  if (tid < 128){ atomicAdd(&S2[cp+tid], ssum[tid]); atomicAdd(&S2[cp+128+tid], ssq[tid]); }
}

// ---------- K8: bn2+relu on pooled extrema, transposed coalesced write ----------
__global__ __launch_bounds__(256) void k_pool(const float* __restrict__ hmax, const float* __restrict__ hmin,
                                              const float* __restrict__ P2, float* __restrict__ out1){
  __shared__ float ot[128*65];
  __shared__ float scs[128], shs[128];
  int tid = threadIdx.x, blk = blockIdx.x;
  int b = blk >> 4, m0 = (blk & 15) * 64;
  if (tid < 128){ scs[tid]=P2[tid]; shs[tid]=P2[128+tid]; }
  __syncthreads();
  int ml = tid >> 2, oq = tid & 3, o0 = oq*32;
  int gm = b*MM + m0 + ml;
  const float4* xr = (const float4*)(hmax + (size_t)gm*128 + o0);
  const float4* nr = (const float4*)(hmin + (size_t)gm*128 + o0);
  #pragma unroll
  for (int j2=0;j2<8;j2++){
    float4 hx = xr[j2], hn = nr[j2];
    float hv[4] = {hx.x, hx.y, hx.z, hx.w};
    float nv[4] = {hn.x, hn.y, hn.z, hn.w};
    #pragma unroll
    for (int e=0;e<4;e++){
      int c = o0 + j2*4 + e;
      float sc = scs[c], sh = shs[c];
      float h = (sc >= 0.f) ? hv[e] : nv[e];
      ot[c*65 + ml] = fmaxf(fmaf(h, sc, sh), 0.f);
    }
  }
  __syncthreads();
  int o = tid >> 1, mh = tid & 1;
  float* dst = out1 + ((size_t)(b*COUT + o))*MM + m0 + mh*32;
  #pragma unroll
  for (int j2=0;j2<8;j2++){
    float4 v;
    v.x=ot[o*65+mh*32+j2*4+0]; v.y=ot[o*65+mh*32+j2*4+1];
    v.z=ot[o*65+mh*32+j2*4+2]; v.w=ot[o*65+mh*32+j2*4+3];
    *(float4*)(dst + j2*4) = v;
  }
}

extern "C" void kernel_launch(void* const* d_in, const int* in_sizes, int n_in,
                              void* d_out, int out_size, void* d_ws, size_t ws_size,
                              hipStream_t stream) {
  (void)in_sizes; (void)n_in; (void)out_size; (void)ws_size;
  const float* p1 = (const float*)d_in[0];
  const float* x1 = (const float*)d_in[1];
  const float* w1 = (const float*)d_in[2];
  const float* g1 = (const float*)d_in[3];
  const float* b1 = (const float*)d_in[4];
  const float* w2 = (const float*)d_in[5];
  const float* g2 = (const float*)d_in[6];
  const float* b2 = (const float*)d_in[7];
  float* out = (float*)d_out;
  float* ws  = (float*)d_ws;

  // ws layout (float indices); ~94.7 MB total (h2 eliminated)
  __hip_bfloat16* xtb = (__hip_bfloat16*)ws;           // 4,194,304 bf16 = 2,097,152 f
  float4* p1n  = (float4*)(ws + 2097152);              //   262,144 f
  int*   iknn  = (int*)(ws + 2359296);                 //   262,144 i
  float* p2w   = ws + 2621440;                         //    65,536 f
  float* S1    = ws + 2686976;                         //     8,192 f
  float* S2    = ws + 2695168;                         //     8,192 f
  float* P1    = ws + 2703360;                         //       256 f
  float* P2    = ws + 2703616;                         //       256 f
  __hip_bfloat16* h1 = (__hip_bfloat16*)(ws + 2703872);    // 33,554,432 bf16 = 16,777,216 f
  float* hmax  = ws + 19481088;                        // 2,097,152 f
  float* hmin  = ws + 21578240;                        // 2,097,152 f

  float* outp2 = out;            // [B,M,3]
  float* out1  = out + 49152;    // [B,128,M]

  hipMemsetAsync(S1, 0, 16384*sizeof(float), stream);  // S1+S2 contiguous
  k_transpose<<<BB*64, 256, 0, stream>>>(x1, xtb);
  k_prep<<<256, 256, 0, stream>>>(p1, p1n);
  k_fps<<<BB, 512, 0, stream>>>(p1, outp2, p2w);
  k_knn<<<4096, 256, 0, stream>>>(p1n, p2w, iknn);
  k_gemm1<<<4096, 256, 0, stream>>>(xtb, iknn, p1, p2w, w1, h1, S1);
  k_fin<<<1, 128, 0, stream>>>(g1, b1, S1, P1);
  k_gemm2<<<4096, 256, 0, stream>>>(h1, w2, P1, S2, hmax, hmin);
  k_fin<<<1, 128, 0, stream>>>(g2, b2, S2, P2);
  k_pool<<<256, 256, 0, stream>>>(hmax, hmin, P2, out1);
}